// Round 1
// baseline (465.486 us; speedup 1.0000x reference)
//
#include <hip/hip_runtime.h>

#define H 128
#define W 128
#define C 64
#define NB 8
#define KK 9

// ws layout (in floats)
static constexpr size_t XT_OFF  = 0;                       // x_t [N][H][W][C]
static constexpr size_t XT_SZ   = (size_t)NB * H * W * C;  // 8388608
static constexpr size_t CD_OFF  = XT_OFF + XT_SZ;          // coords float2 [N][9][H][W]
static constexpr size_t CD_SZ   = (size_t)NB * KK * H * W * 2;  // 2359296
static constexpr size_t WT_OFF  = CD_OFF + CD_SZ;          // wT [9][c][co]
static constexpr size_t WT_SZ   = (size_t)KK * C * C;      // 36864
static constexpr size_t SUM_OFF = WT_OFF + WT_SZ;          // 128 floats (sum, sumsq)

// ---------------- prep: NCHW->NHWC transpose of x, transpose w -> wT[k][c][co], zero sums
__global__ __launch_bounds__(256) void prep_kernel(const float* __restrict__ x,
                                                   const float* __restrict__ w,
                                                   float* __restrict__ ws) {
  int b = blockIdx.x, t = threadIdx.x;
  if (b < 1024) {
    __shared__ float lds[64 * 129];
    int n = b >> 7, h = b & 127;
    const float* xp = x + ((size_t)n * C) * H * W + (size_t)h * W;
    for (int i = t; i < 8192; i += 256) {
      int c = i >> 7, ww = i & 127;
      lds[c * 129 + ww] = xp[(size_t)c * H * W + ww];
    }
    __syncthreads();
    float* xt = ws + XT_OFF + (((size_t)n * H + h) * W) * C;
    for (int i = t; i < 8192; i += 256) {
      int ww = i >> 6, c = i & 63;
      xt[(size_t)ww * C + c] = lds[c * 129 + ww];
    }
  } else if (b < 1040) {
    int base = (b - 1024) * 2304;
    for (int i = t; i < 2304; i += 256) {
      int idx = base + i;               // idx = co*576 + c*9 + kk
      int co = idx / 576;
      int rem = idx % 576;
      int c = rem / 9, kk = rem % 9;
      ws[WT_OFF + (size_t)kk * 4096 + c * 64 + co] = w[idx];
    }
  } else {
    if (t < 128) ws[SUM_OFF + t] = 0.0f;
  }
}

// ---------------- offset conv (3x3, pad 1) -> sample coords (ys,xs) per (n,k,h,w)
__global__ __launch_bounds__(256) void offs_kernel(const float* __restrict__ x,
                                                   const float* __restrict__ w_off,
                                                   const float* __restrict__ b_off,
                                                   float* __restrict__ ws) {
  int b = blockIdx.x;
  int n = b >> 6;
  int tile = b & 63;
  int ty0 = (tile >> 3) << 4;
  int tx0 = (tile & 7) << 4;
  int t = threadIdx.x;
  int ty = t >> 4, tx = t & 15;
  __shared__ float lx[16 * 18 * 18];
  float acc[18];
#pragma unroll
  for (int o = 0; o < 18; ++o) acc[o] = 0.f;

  for (int ch = 0; ch < 4; ++ch) {
    __syncthreads();
    for (int i = t; i < 16 * 324; i += 256) {
      int c16 = i / 324, r = i % 324;
      int ry = r / 18, rx = r % 18;
      int gy = ty0 + ry - 1, gx = tx0 + rx - 1;
      float v = 0.f;
      if (gy >= 0 && gy < H && gx >= 0 && gx < W)
        v = x[(((size_t)n * C + ch * 16 + c16) * H + gy) * W + gx];
      lx[i] = v;
    }
    __syncthreads();
    for (int c16 = 0; c16 < 16; ++c16) {
      int c = ch * 16 + c16;
      float xr[9];
#pragma unroll
      for (int dy = 0; dy < 3; ++dy)
#pragma unroll
        for (int dx = 0; dx < 3; ++dx)
          xr[dy * 3 + dx] = lx[c16 * 324 + (ty + dy) * 18 + (tx + dx)];
      const float* wp = w_off + (size_t)c * 9;  // w_off[(o*64+c)*9 + t9]
#pragma unroll
      for (int o = 0; o < 18; ++o) {
#pragma unroll
        for (int t9 = 0; t9 < 9; ++t9)
          acc[o] += xr[t9] * wp[(size_t)o * 576 + t9];
      }
    }
  }
  int h = ty0 + ty, ww = tx0 + tx;
  float2* cd = (float2*)(ws + CD_OFF);
#pragma unroll
  for (int k = 0; k < 9; ++k) {
    float ys = (float)(k / 3 + h - 1) + acc[2 * k] + b_off[2 * k];
    float xs = (float)(k % 3 + ww - 1) + acc[2 * k + 1] + b_off[2 * k + 1];
    cd[(((size_t)n * 9 + k) * H + h) * W + ww] = make_float2(ys, xs);
  }
}

// ---------------- deformable conv: gather + 64x64 GEMM per tap, bias, partial BN sums
__global__ __launch_bounds__(256) void conv_kernel(const float* __restrict__ wsr,
                                                   const float* __restrict__ bias,
                                                   float* __restrict__ out,
                                                   float* __restrict__ sums) {
  int b = blockIdx.x;
  int n = b >> 8;
  int tile = b & 255;
  int ty0 = (tile >> 4) << 3;
  int tx0 = (tile & 15) << 3;
  int t = threadIdx.x;
  int wv = t >> 6, ln = t & 63;

  __shared__ float2 cds[9 * 64];
  __shared__ float s_w[64 * 68];
  __shared__ float s_val[64 * 68];
  __shared__ float red[2 * 16 * 65];

  const float* xt = wsr + XT_OFF;
  const float2* cd = (const float2*)(wsr + CD_OFF);
  const float* wT = wsr + WT_OFF;

  for (int i = t; i < 576; i += 256) {
    int k = i >> 6, pos = i & 63;
    int h = ty0 + (pos >> 3), ww = tx0 + (pos & 7);
    cds[i] = cd[(((size_t)n * 9 + k) * H + h) * W + ww];
  }

  float acc[4][4];
#pragma unroll
  for (int i = 0; i < 4; ++i)
#pragma unroll
    for (int j = 0; j < 4; ++j) acc[i][j] = 0.f;

  int co_b = (t & 15) * 4;
  int pos_b = (t >> 4) * 4;
  const float* xtn = xt + (size_t)n * H * W * C;

  for (int k = 0; k < 9; ++k) {
    __syncthreads();
    // stage w tap: s_w[c][co] = w[co][c][k]
    for (int i = t; i < 4096; i += 256)
      s_w[(i >> 6) * 68 + (i & 63)] = wT[(size_t)k * 4096 + i];
    // gather val[c=ln][pos] for 16 positions per wave
    for (int pp = 0; pp < 16; ++pp) {
      int pos = wv * 16 + pp;
      float2 c2 = cds[k * 64 + pos];
      float ys = c2.x, xs = c2.y;
      float y0f = floorf(ys), x0f = floorf(xs);
      float wy = ys - y0f, wx = xs - x0f;
      int iy0 = (int)y0f, ix0 = (int)x0f;
      int iy1 = iy0 + 1, ix1 = ix0 + 1;
      float m00 = (iy0 >= 0 && iy0 < H && ix0 >= 0 && ix0 < W) ? 1.f : 0.f;
      float m01 = (iy0 >= 0 && iy0 < H && ix1 >= 0 && ix1 < W) ? 1.f : 0.f;
      float m10 = (iy1 >= 0 && iy1 < H && ix0 >= 0 && ix0 < W) ? 1.f : 0.f;
      float m11 = (iy1 >= 0 && iy1 < H && ix1 >= 0 && ix1 < W) ? 1.f : 0.f;
      int yc0 = min(max(iy0, 0), H - 1), yc1 = min(max(iy1, 0), H - 1);
      int xc0 = min(max(ix0, 0), W - 1), xc1 = min(max(ix1, 0), W - 1);
      float w00 = (1.f - wy) * (1.f - wx) * m00;
      float w01 = (1.f - wy) * wx * m01;
      float w10 = wy * (1.f - wx) * m10;
      float w11 = wy * wx * m11;
      float v = w00 * xtn[((size_t)yc0 * W + xc0) * C + ln]
              + w01 * xtn[((size_t)yc0 * W + xc1) * C + ln]
              + w10 * xtn[((size_t)yc1 * W + xc0) * C + ln]
              + w11 * xtn[((size_t)yc1 * W + xc1) * C + ln];
      s_val[ln * 68 + (pos ^ ((ln >> 3) << 2))] = v;
    }
    __syncthreads();
    // GEMM: acc[co 4][pos 4] += w[co][c] * val[c][pos]
    for (int c = 0; c < 64; ++c) {
      float4 w4 = *(const float4*)&s_w[c * 68 + co_b];
      float4 v4 = *(const float4*)&s_val[c * 68 + (pos_b ^ ((c >> 3) << 2))];
      acc[0][0] += w4.x * v4.x; acc[0][1] += w4.x * v4.y; acc[0][2] += w4.x * v4.z; acc[0][3] += w4.x * v4.w;
      acc[1][0] += w4.y * v4.x; acc[1][1] += w4.y * v4.y; acc[1][2] += w4.y * v4.z; acc[1][3] += w4.y * v4.w;
      acc[2][0] += w4.z * v4.x; acc[2][1] += w4.z * v4.y; acc[2][2] += w4.z * v4.z; acc[2][3] += w4.z * v4.w;
      acc[3][0] += w4.w * v4.x; acc[3][1] += w4.w * v4.y; acc[3][2] += w4.w * v4.z; acc[3][3] += w4.w * v4.w;
    }
  }

  // bias + write preBN into d_out
  float b4[4];
#pragma unroll
  for (int i = 0; i < 4; ++i) b4[i] = bias[co_b + i];
  int h = ty0 + (pos_b >> 3), wc = tx0 + (pos_b & 7);
#pragma unroll
  for (int i = 0; i < 4; ++i) {
#pragma unroll
    for (int j = 0; j < 4; ++j) acc[i][j] += b4[i];
    float4 o4 = make_float4(acc[i][0], acc[i][1], acc[i][2], acc[i][3]);
    *(float4*)&out[(((size_t)n * 64 + co_b + i) * H + h) * W + wc] = o4;
  }

  // per-block channel partial sums -> atomics
  int grp = t >> 4;
#pragma unroll
  for (int i = 0; i < 4; ++i) {
    float s1 = acc[i][0] + acc[i][1] + acc[i][2] + acc[i][3];
    float s2 = acc[i][0] * acc[i][0] + acc[i][1] * acc[i][1] +
               acc[i][2] * acc[i][2] + acc[i][3] * acc[i][3];
    red[grp * 65 + co_b + i] = s1;
    red[16 * 65 + grp * 65 + co_b + i] = s2;
  }
  __syncthreads();
  if (t < 64) {
    float s1 = 0.f, s2 = 0.f;
#pragma unroll
    for (int g = 0; g < 16; ++g) {
      s1 += red[g * 65 + t];
      s2 += red[16 * 65 + g * 65 + t];
    }
    atomicAdd(&sums[t], s1);
    atomicAdd(&sums[64 + t], s2);
  }
}

// ---------------- BN apply (in place on d_out)
__global__ __launch_bounds__(256) void bn_kernel(float* __restrict__ out,
                                                 const float* __restrict__ sums,
                                                 const float* __restrict__ gamma,
                                                 const float* __restrict__ beta) {
  size_t i4 = (size_t)blockIdx.x * 256 + threadIdx.x;
  size_t e = i4 * 4;
  int co = (int)((e >> 14) & 63);
  float s1 = sums[co], s2 = sums[64 + co];
  const float inv_n = 1.f / 131072.f;
  float mean = s1 * inv_n;
  float var = s2 * inv_n - mean * mean;
  float iv = rsqrtf(var + 1e-5f);
  float sc = gamma[co] * iv;
  float sh = beta[co] - mean * sc;
  float4 v = ((float4*)out)[i4];
  v.x = v.x * sc + sh;
  v.y = v.y * sc + sh;
  v.z = v.z * sc + sh;
  v.w = v.w * sc + sh;
  ((float4*)out)[i4] = v;
}

extern "C" void kernel_launch(void* const* d_in, const int* in_sizes, int n_in,
                              void* d_out, int out_size, void* d_ws, size_t ws_size,
                              hipStream_t stream) {
  (void)in_sizes; (void)n_in; (void)out_size; (void)ws_size;
  const float* x     = (const float*)d_in[0];
  const float* w_off = (const float*)d_in[1];
  const float* b_off = (const float*)d_in[2];
  const float* w     = (const float*)d_in[3];
  const float* bias  = (const float*)d_in[4];
  const float* gamma = (const float*)d_in[5];
  const float* beta  = (const float*)d_in[6];
  float* ws  = (float*)d_ws;
  float* out = (float*)d_out;

  hipLaunchKernelGGL(prep_kernel, dim3(1041), dim3(256), 0, stream, x, w, ws);
  hipLaunchKernelGGL(offs_kernel, dim3(512), dim3(256), 0, stream, x, w_off, b_off, ws);
  hipLaunchKernelGGL(conv_kernel, dim3(2048), dim3(256), 0, stream, ws, bias, out, ws + SUM_OFF);
  hipLaunchKernelGGL(bn_kernel, dim3(8192), dim3(256), 0, stream, out, ws + SUM_OFF, gamma, beta);
}